// Round 8
// baseline (585.469 us; speedup 1.0000x reference)
//
#include <hip/hip_runtime.h>
#include <hip/hip_bf16.h>
#include <cstdint>

#define HD 1024
#define ID 4096
#define NE 8
#define NTOK 4096
#define NASS 8192
#define NWL 72

typedef unsigned short u16;
typedef __attribute__((ext_vector_type(8))) __bf16 bf16x8;
typedef __attribute__((ext_vector_type(4))) float f32x4;

__device__ __forceinline__ void async16(void* lds, const void* g) {
  __builtin_amdgcn_global_load_lds(
      (const __attribute__((address_space(1))) uint32_t*)g,
      (__attribute__((address_space(3))) uint32_t*)lds, 16, 0, 0);
}

__device__ __forceinline__ u16 f2b(float f) {
  __bf16 h = (__bf16)f;
  return __builtin_bit_cast(u16, h);
}

__device__ __forceinline__ bf16x8 cvt8(const float* p) {
  const float4* q = (const float4*)p;
  float4 a = q[0], b = q[1];
  bf16x8 v;
  v[0] = (__bf16)a.x; v[1] = (__bf16)a.y; v[2] = (__bf16)a.z; v[3] = (__bf16)a.w;
  v[4] = (__bf16)b.x; v[5] = (__bf16)b.y; v[6] = (__bf16)b.z; v[7] = (__bf16)b.w;
  return v;
}

__device__ __forceinline__ bf16x8 cvt8v(float4 a, float4 b) {
  bf16x8 v;
  v[0] = (__bf16)a.x; v[1] = (__bf16)a.y; v[2] = (__bf16)a.z; v[3] = (__bf16)a.w;
  v[4] = (__bf16)b.x; v[5] = (__bf16)b.y; v[6] = (__bf16)b.z; v[7] = (__bf16)b.w;
  return v;
}

// ---- prep: x fp32->bf16 + zero out (tiny: 42 MB) ----
__global__ void k_pre(const float* __restrict__ x, u16* __restrict__ xb,
                      float* __restrict__ out) {
  size_t v = (size_t)blockIdx.x * 256 + threadIdx.x;   // vec8 index, 524288 total
  size_t i8 = v * 8;
  *(bf16x8*)(xb + i8) = cvt8(x + i8);
  float4 z = {0.f, 0.f, 0.f, 0.f};
  float4* op = (float4*)(out + i8);
  op[0] = z; op[1] = z;
}

// ---- fused count + scan + place + worklist (single block) ----
__global__ void k_meta(const int* __restrict__ eidx, int* __restrict__ offsets,
                       int* __restrict__ wl, int* __restrict__ tokl) {
  __shared__ int cnt[NE], offs_s[NE + 1], cur[NE];
  int t = threadIdx.x;
  if (t < NE) cnt[t] = 0;
  __syncthreads();
  for (int i = t; i < NASS; i += 1024) atomicAdd(&cnt[eidx[i]], 1);
  __syncthreads();
  if (t == 0) {
    int s = 0;
    for (int e = 0; e < NE; ++e) { offs_s[e] = s; s += cnt[e]; }
    offs_s[NE] = s;
    int w = 0;
    for (int e = 0; e < NE; ++e)
      for (int mt = 0; mt * 128 < cnt[e]; ++mt) wl[w++] = (e << 16) | mt;
    for (; w < NWL; ++w) wl[w] = -1;
  }
  if (t < NE) cur[t] = 0;
  __syncthreads();
  for (int i = t; i < NASS; i += 1024) {
    int e = eidx[i];
    int p = atomicAdd(&cur[e], 1);
    tokl[offs_s[e] + p] = i;   // assignment id (token = i>>1, weight = ewt[i])
  }
  if (t <= NE) offsets[t] = offs_s[t];
}

// ---- GEMM1: interm = silu(X@G^T)*(X@U^T); BM=128 BN=128 dual, BK=64 ----
// B operands read as fp32 DIRECTLY from gate/up; reg-staged cvt -> bf16 LDS.
// T14 split: B-loads for tile k+1 issued before compute(k); cvt+write after
// the barrier. A stays on global_load_lds. blocks bx>=32 convert down.
__global__ __launch_bounds__(256, 2) void k_g1(
    const u16* __restrict__ xb, const float* __restrict__ gate,
    const float* __restrict__ up, const float* __restrict__ down,
    u16* __restrict__ wd, const int* __restrict__ offsets,
    const int* __restrict__ wl, const int* __restrict__ tokl,
    u16* __restrict__ interm) {
  const int bx = blockIdx.x;
  const int t = threadIdx.x;
  if (bx >= 32) {                     // down-proj conversion lane
    int cid = (bx - 32) + 32 * (int)blockIdx.y;
    if (cid < 2048) {
#pragma unroll
      for (int l = 0; l < 8; ++l) {
        size_t i8 = (((size_t)cid * 8 + l) * 256 + t) * 8;
        *(bf16x8*)(wd + i8) = cvt8(down + i8);
      }
    }
    return;
  }
  const int wle = wl[blockIdx.y];
  if (wle < 0) return;
  const int e = wle >> 16;
  const int m0 = (wle & 0xffff) << 7;
  const int offs = offsets[e];
  const int Me = offsets[e + 1] - offs;
  const int n0 = bx * 128;
  const int lane = t & 63, wv = t >> 6;
  const int wm = wv & 1, wn = wv >> 1;

  __shared__ __align__(16) u16 As[128 * 64];
  __shared__ __align__(16) u16 Bg[128 * 64];
  __shared__ __align__(16) u16 Bu[128 * 64];

  const u16* asrc[4];
#pragma unroll
  for (int p = 0; p < 4; ++p) {
    int c = p * 256 + t;
    int r = c >> 3, c8 = c & 7;
    int row = m0 + r; if (row > Me - 1) row = Me - 1;
    asrc[p] = xb + (size_t)(tokl[offs + row] >> 1) * HD + c8 * 8;
  }
  // B fp32 sources: thread t covers tile-row br = t>>1, k-half bh = (t&1)*32
  const int br = t >> 1;
  const int bh = (t & 1) * 32;
  const float* gsrc = gate + ((size_t)e * ID + n0 + br) * HD + bh;
  const float* usrc = up   + ((size_t)e * ID + n0 + br) * HD + bh;
  u16* bgdst = Bg + br * 64 + bh;
  u16* budst = Bu + br * 64 + bh;

  float4 gv[8], uv[8];
#define LOADB(ks)                                                  \
  { _Pragma("unroll") for (int q = 0; q < 8; ++q) {                \
      gv[q] = ((const float4*)(gsrc + (ks) * 64))[q];              \
      uv[q] = ((const float4*)(usrc + (ks) * 64))[q];              \
    } }
#define WRITEB()                                                   \
  { _Pragma("unroll") for (int q = 0; q < 4; ++q) {                \
      ((bf16x8*)bgdst)[q] = cvt8v(gv[2 * q], gv[2 * q + 1]);       \
      ((bf16x8*)budst)[q] = cvt8v(uv[2 * q], uv[2 * q + 1]);       \
    } }
#define STAGEA(ks)                                                 \
  { _Pragma("unroll") for (int p = 0; p < 4; ++p)                  \
      async16((char*)As + (p * 256 + wv * 64) * 16, asrc[p] + (ks) * 64); }

  f32x4 accg[4][4], accu[4][4];
#pragma unroll
  for (int mi = 0; mi < 4; ++mi)
#pragma unroll
    for (int ni = 0; ni < 4; ++ni) {
      accg[mi][ni] = (f32x4){0.f, 0.f, 0.f, 0.f};
      accu[mi][ni] = (f32x4){0.f, 0.f, 0.f, 0.f};
    }

  // prologue: tile 0 into LDS
  LOADB(0);
  WRITEB();
  STAGEA(0);
  __syncthreads();

  const int lrow = lane & 15, lk = (lane >> 4) * 8;
#pragma unroll 1
  for (int ks = 0; ks < HD / 64; ++ks) {
    if (ks < 15) LOADB(ks + 1);        // in flight across the MFMA phase
#pragma unroll
    for (int kk = 0; kk < 2; ++kk) {
      bf16x8 af[4], bg[4], bu[4];
#pragma unroll
      for (int mi = 0; mi < 4; ++mi)
        af[mi] = *(const bf16x8*)&As[(wm * 64 + mi * 16 + lrow) * 64 + kk * 32 + lk];
#pragma unroll
      for (int ni = 0; ni < 4; ++ni) {
        bg[ni] = *(const bf16x8*)&Bg[(wn * 64 + ni * 16 + lrow) * 64 + kk * 32 + lk];
        bu[ni] = *(const bf16x8*)&Bu[(wn * 64 + ni * 16 + lrow) * 64 + kk * 32 + lk];
      }
#pragma unroll
      for (int mi = 0; mi < 4; ++mi)
#pragma unroll
        for (int ni = 0; ni < 4; ++ni) {
          accg[mi][ni] = __builtin_amdgcn_mfma_f32_16x16x32_bf16(af[mi], bg[ni], accg[mi][ni], 0, 0, 0);
          accu[mi][ni] = __builtin_amdgcn_mfma_f32_16x16x32_bf16(af[mi], bu[ni], accu[mi][ni], 0, 0, 0);
        }
    }
    __syncthreads();                   // all reads of tile ks done
    if (ks < 15) {
      WRITEB();                        // loads have drained under compute
      STAGEA(ks + 1);
    }
    __syncthreads();                   // tile ks+1 ready (implicit vm/lgkm drain)
  }
#undef LOADB
#undef WRITEB
#undef STAGEA

#pragma unroll
  for (int mi = 0; mi < 4; ++mi) {
    int rb = wm * 64 + mi * 16 + (lane >> 4) * 4;
#pragma unroll
    for (int ni = 0; ni < 4; ++ni) {
      int col = n0 + wn * 64 + ni * 16 + (lane & 15);
#pragma unroll
      for (int j = 0; j < 4; ++j) {
        int row = m0 + rb + j;
        if (row < Me) {
          float g = accg[mi][ni][j], u = accu[mi][ni][j];
          float s = g / (1.f + __expf(-g));
          interm[(size_t)(offs + row) * ID + col] = f2b(s * u);
        }
      }
    }
  }
}

// ---- GEMM2: out[tok,:] += ewt[aid] * (interm @ D^T); BM=128 BN=256 ----
__global__ __launch_bounds__(256, 2) void k_g2(
    const u16* __restrict__ interm, const u16* __restrict__ wd,
    const int* __restrict__ offsets, const int* __restrict__ wl,
    const int* __restrict__ tokl, const float* __restrict__ ewt,
    float* __restrict__ out) {
  const int wle = wl[blockIdx.y];
  if (wle < 0) return;
  const int e = wle >> 16;
  const int m0 = (wle & 0xffff) << 7;
  const int offs = offsets[e];
  const int Me = offsets[e + 1] - offs;
  const int n0 = blockIdx.x * 256;
  const int t = threadIdx.x, lane = t & 63, wv = t >> 6;
  const int wm = wv & 1, wn = wv >> 1;   // wm,wn in {0,1}

  __shared__ __align__(16) u16 As[128 * 64];
  __shared__ __align__(16) u16 Bs[256 * 64];

  const u16* asrc[4];
#pragma unroll
  for (int p = 0; p < 4; ++p) {
    int c = p * 256 + t;
    int r = c >> 3, c8 = c & 7;
    int row = m0 + r; if (row > Me - 1) row = Me - 1;
    asrc[p] = interm + (size_t)(offs + row) * ID + c8 * 8;
  }
  const u16* bsrc[8];
#pragma unroll
  for (int p = 0; p < 8; ++p) {
    int c = p * 256 + t;
    int r = c >> 3, c8 = c & 7;
    bsrc[p] = wd + ((size_t)e * HD + n0 + r) * ID + c8 * 8;
  }

  f32x4 acc[4][8];
#pragma unroll
  for (int mi = 0; mi < 4; ++mi)
#pragma unroll
    for (int ni = 0; ni < 8; ++ni) acc[mi][ni] = (f32x4){0.f, 0.f, 0.f, 0.f};

  const int lrow = lane & 15, lk = (lane >> 4) * 8;
#pragma unroll 1
  for (int ks = 0; ks < ID / 64; ++ks) {
    __syncthreads();
#pragma unroll
    for (int p = 0; p < 4; ++p)
      async16((char*)As + (p * 256 + wv * 64) * 16, asrc[p]);
#pragma unroll
    for (int p = 0; p < 8; ++p)
      async16((char*)Bs + (p * 256 + wv * 64) * 16, bsrc[p]);
    __syncthreads();
#pragma unroll
    for (int kk = 0; kk < 2; ++kk) {
      bf16x8 af[4], bfr[8];
#pragma unroll
      for (int mi = 0; mi < 4; ++mi)
        af[mi] = *(const bf16x8*)&As[(wm * 64 + mi * 16 + lrow) * 64 + kk * 32 + lk];
#pragma unroll
      for (int ni = 0; ni < 8; ++ni)
        bfr[ni] = *(const bf16x8*)&Bs[(wn * 128 + ni * 16 + lrow) * 64 + kk * 32 + lk];
#pragma unroll
      for (int mi = 0; mi < 4; ++mi)
#pragma unroll
        for (int ni = 0; ni < 8; ++ni)
          acc[mi][ni] = __builtin_amdgcn_mfma_f32_16x16x32_bf16(af[mi], bfr[ni], acc[mi][ni], 0, 0, 0);
    }
#pragma unroll
    for (int p = 0; p < 4; ++p) asrc[p] += 64;
#pragma unroll
    for (int p = 0; p < 8; ++p) bsrc[p] += 64;
  }

#pragma unroll
  for (int mi = 0; mi < 4; ++mi) {
    int rb = wm * 64 + mi * 16 + (lane >> 4) * 4;
#pragma unroll
    for (int j = 0; j < 4; ++j) {
      int row = m0 + rb + j;
      if (row < Me) {
        int aid = tokl[offs + row];
        float w = ewt[aid];
        float* orow = out + (size_t)(aid >> 1) * HD;
#pragma unroll
        for (int ni = 0; ni < 8; ++ni) {
          int col = n0 + wn * 128 + ni * 16 + (lane & 15);
          atomicAdd(orow + col, w * acc[mi][ni][j]);
        }
      }
    }
  }
}

extern "C" void kernel_launch(void* const* d_in, const int* in_sizes, int n_in,
                              void* d_out, int out_size, void* d_ws, size_t ws_size,
                              hipStream_t stream) {
  const float* x    = (const float*)d_in[0];
  const int*   eidx = (const int*)d_in[1];
  const float* ewt  = (const float*)d_in[2];
  const float* gate = (const float*)d_in[3];
  const float* up   = (const float*)d_in[4];
  const float* down = (const float*)d_in[5];
  float* out = (float*)d_out;
  char* ws = (char*)d_ws;

  // layout (total ~148 MiB, well under proven budget):
  constexpr size_t OFF_INTERM = 0;           // 64 MiB bf16 interm
  constexpr size_t OFF_XB     = 67108864;    // 8 MiB bf16 x
  constexpr size_t OFF_META   = 75497472;    // offsets @ +0, wl @ +64
  constexpr size_t OFF_TOK    = 75498496;    // 32 KiB assignment ids
  constexpr size_t OFF_WD     = 75531264;    // 64 MiB bf16 down

  u16* interm  = (u16*)(ws + OFF_INTERM);
  u16* xb      = (u16*)(ws + OFF_XB);
  int* offsets = (int*)(ws + OFF_META);
  int* wl      = (int*)(ws + OFF_META + 64);
  int* tokl    = (int*)(ws + OFF_TOK);
  u16* wd      = (u16*)(ws + OFF_WD);

  k_pre<<<dim3(2048), dim3(256), 0, stream>>>(x, xb, out);
  k_meta<<<dim3(1), dim3(1024), 0, stream>>>(eidx, offsets, wl, tokl);
  k_g1<<<dim3(64, NWL), dim3(256), 0, stream>>>(xb, gate, up, down, wd, offsets, wl, tokl, interm);
  k_g2<<<dim3(HD / 256, NWL), dim3(256), 0, stream>>>(interm, wd, offsets, wl, tokl, ewt, out);
}

// Round 9
// 460.504 us; speedup vs baseline: 1.2714x; 1.2714x over previous
//
#include <hip/hip_runtime.h>
#include <hip/hip_bf16.h>
#include <cstdint>

#define HD 1024
#define ID 4096
#define NE 8
#define NTOK 4096
#define NASS 8192
#define NWL 72

typedef unsigned short u16;
typedef __attribute__((ext_vector_type(8))) __bf16 bf16x8;
typedef __attribute__((ext_vector_type(4))) float f32x4;

__device__ __forceinline__ void async16(void* lds, const void* g) {
  __builtin_amdgcn_global_load_lds(
      (const __attribute__((address_space(1))) uint32_t*)g,
      (__attribute__((address_space(3))) uint32_t*)lds, 16, 0, 0);
}

__device__ __forceinline__ u16 f2b(float f) {
  __bf16 h = (__bf16)f;
  return __builtin_bit_cast(u16, h);
}

__device__ __forceinline__ bf16x8 cvt8(const float* p) {
  const float4* q = (const float4*)p;
  float4 a = q[0], b = q[1];
  bf16x8 v;
  v[0] = (__bf16)a.x; v[1] = (__bf16)a.y; v[2] = (__bf16)a.z; v[3] = (__bf16)a.w;
  v[4] = (__bf16)b.x; v[5] = (__bf16)b.y; v[6] = (__bf16)b.z; v[7] = (__bf16)b.w;
  return v;
}

// ---- prep: x, gate, up fp32->bf16; zero out. Grid-stride, 2048 blocks ----
__global__ void k_pre(const float* __restrict__ x, const float* __restrict__ gate,
                      const float* __restrict__ up, u16* __restrict__ xb,
                      u16* __restrict__ wg, u16* __restrict__ wu,
                      float* __restrict__ out) {
  const size_t stride = (size_t)gridDim.x * 256;
  for (size_t v = (size_t)blockIdx.x * 256 + threadIdx.x; v < 8912896ull; v += stride) {
    const float* src; u16* dst; size_t off;
    if (v < 524288ull)        { src = x;    dst = xb; off = v;
      float4 z = {0.f, 0.f, 0.f, 0.f};
      float4* op = (float4*)(out + off * 8);
      op[0] = z; op[1] = z;
    }
    else if (v < 4718592ull)  { src = gate; dst = wg; off = v - 524288ull; }
    else                      { src = up;   dst = wu; off = v - 4718592ull; }
    size_t i8 = off * 8;
    *(bf16x8*)(dst + i8) = cvt8(src + i8);
  }
}

// ---- fused count + scan + place + worklist (single block) ----
__global__ void k_meta(const int* __restrict__ eidx, int* __restrict__ offsets,
                       int* __restrict__ wl, int* __restrict__ tokl) {
  __shared__ int cnt[NE], offs_s[NE + 1], cur[NE];
  int t = threadIdx.x;
  if (t < NE) cnt[t] = 0;
  __syncthreads();
  for (int i = t; i < NASS; i += 1024) atomicAdd(&cnt[eidx[i]], 1);
  __syncthreads();
  if (t == 0) {
    int s = 0;
    for (int e = 0; e < NE; ++e) { offs_s[e] = s; s += cnt[e]; }
    offs_s[NE] = s;
    int w = 0;
    for (int e = 0; e < NE; ++e)
      for (int mt = 0; mt * 128 < cnt[e]; ++mt) wl[w++] = (e << 16) | mt;
    for (; w < NWL; ++w) wl[w] = -1;
  }
  if (t < NE) cur[t] = 0;
  __syncthreads();
  for (int i = t; i < NASS; i += 1024) {
    int e = eidx[i];
    int p = atomicAdd(&cur[e], 1);
    tokl[offs_s[e] + p] = i;   // assignment id (token = i>>1, weight = ewt[i])
  }
  if (t <= NE) offsets[t] = offs_s[t];
}

// ---- GEMM1: interm = silu(X@G^T)*(X@U^T); BM=128 BN=128 dual, BK=32 ----
// Double-buffered, single __syncthreads per K-step (T3-minimum recipe):
// STAGE(next) issued BEFORE compute(cur); barrier drains both. 48 KB LDS.
// blocks bx>=32 convert down fp32->bf16 (hidden under gemm compute).
__global__ __launch_bounds__(256, 2) void k_g1(
    const u16* __restrict__ xb, const u16* __restrict__ wg, const u16* __restrict__ wu,
    const float* __restrict__ down, u16* __restrict__ wd,
    const int* __restrict__ offsets, const int* __restrict__ wl,
    const int* __restrict__ tokl, u16* __restrict__ interm) {
  const int bx = blockIdx.x;
  const int t = threadIdx.x;
  if (bx >= 32) {                     // down-proj conversion lane
    int cid = (bx - 32) + 32 * (int)blockIdx.y;
    if (cid < 2048) {
#pragma unroll
      for (int l = 0; l < 8; ++l) {
        size_t i8 = (((size_t)cid * 8 + l) * 256 + t) * 8;
        *(bf16x8*)(wd + i8) = cvt8(down + i8);
      }
    }
    return;
  }
  const int wle = wl[blockIdx.y];
  if (wle < 0) return;
  const int e = wle >> 16;
  const int m0 = (wle & 0xffff) << 7;
  const int offs = offsets[e];
  const int Me = offsets[e + 1] - offs;
  const int n0 = bx * 128;
  const int lane = t & 63, wv = t >> 6;
  const int wm = wv & 1, wn = wv >> 1;

  // [2 buffers][128 rows][32 cols] bf16 = 8 KB per buffer per array
  __shared__ __align__(16) u16 As[2][128 * 32];
  __shared__ __align__(16) u16 Bg[2][128 * 32];
  __shared__ __align__(16) u16 Bu[2][128 * 32];

  // staging: chunk c = p*256+t (p=0,1), row = c>>2, col8 = (c&3)*8
  const u16* asrc[2];
#pragma unroll
  for (int p = 0; p < 2; ++p) {
    int c = p * 256 + t;
    int r = c >> 2, c8 = (c & 3) * 8;
    int row = m0 + r; if (row > Me - 1) row = Me - 1;
    asrc[p] = xb + (size_t)(tokl[offs + row] >> 1) * HD + c8;
  }
  const u16 *bgsrc[2], *busrc[2];
#pragma unroll
  for (int p = 0; p < 2; ++p) {
    int c = p * 256 + t;
    int r = c >> 2, c8 = (c & 3) * 8;
    size_t boff = ((size_t)e * ID + n0 + r) * HD + c8;
    bgsrc[p] = wg + boff;
    busrc[p] = wu + boff;
  }

#define STAGE1(b, ks)                                                           \
  {                                                                             \
    _Pragma("unroll") for (int p = 0; p < 2; ++p) {                             \
      async16((char*)As[b] + (p * 256 + wv * 64) * 16, asrc[p] + (ks) * 32);    \
      async16((char*)Bg[b] + (p * 256 + wv * 64) * 16, bgsrc[p] + (ks) * 32);   \
      async16((char*)Bu[b] + (p * 256 + wv * 64) * 16, busrc[p] + (ks) * 32);   \
    }                                                                           \
  }

  f32x4 accg[4][4], accu[4][4];
#pragma unroll
  for (int mi = 0; mi < 4; ++mi)
#pragma unroll
    for (int ni = 0; ni < 4; ++ni) {
      accg[mi][ni] = (f32x4){0.f, 0.f, 0.f, 0.f};
      accu[mi][ni] = (f32x4){0.f, 0.f, 0.f, 0.f};
    }

  STAGE1(0, 0);
  __syncthreads();                     // tile 0 resident

  const int lrow = lane & 15, lk = (lane >> 4) * 8;
#pragma unroll 1
  for (int ks = 0; ks < HD / 32; ++ks) {
    const int curb = ks & 1;
    if (ks < HD / 32 - 1) STAGE1(curb ^ 1, ks + 1);   // in flight under MFMA
    bf16x8 af[4], bg[4], bu[4];
#pragma unroll
    for (int mi = 0; mi < 4; ++mi)
      af[mi] = *(const bf16x8*)&As[curb][(wm * 64 + mi * 16 + lrow) * 32 + lk];
#pragma unroll
    for (int ni = 0; ni < 4; ++ni) {
      bg[ni] = *(const bf16x8*)&Bg[curb][(wn * 64 + ni * 16 + lrow) * 32 + lk];
      bu[ni] = *(const bf16x8*)&Bu[curb][(wn * 64 + ni * 16 + lrow) * 32 + lk];
    }
#pragma unroll
    for (int mi = 0; mi < 4; ++mi)
#pragma unroll
      for (int ni = 0; ni < 4; ++ni) {
        accg[mi][ni] = __builtin_amdgcn_mfma_f32_16x16x32_bf16(af[mi], bg[ni], accg[mi][ni], 0, 0, 0);
        accu[mi][ni] = __builtin_amdgcn_mfma_f32_16x16x32_bf16(af[mi], bu[ni], accu[mi][ni], 0, 0, 0);
      }
    __syncthreads();                   // reads of cur done + next tile resident
  }
#undef STAGE1

#pragma unroll
  for (int mi = 0; mi < 4; ++mi) {
    int rb = wm * 64 + mi * 16 + (lane >> 4) * 4;
#pragma unroll
    for (int ni = 0; ni < 4; ++ni) {
      int col = n0 + wn * 64 + ni * 16 + (lane & 15);
#pragma unroll
      for (int j = 0; j < 4; ++j) {
        int row = m0 + rb + j;
        if (row < Me) {
          float g = accg[mi][ni][j], u = accu[mi][ni][j];
          float s = g / (1.f + __expf(-g));
          interm[(size_t)(offs + row) * ID + col] = f2b(s * u);
        }
      }
    }
  }
}

// ---- GEMM2: out[tok,:] += ewt[aid] * (interm @ D^T); BM=128 BN=256 ----
__global__ __launch_bounds__(256, 2) void k_g2(
    const u16* __restrict__ interm, const u16* __restrict__ wd,
    const int* __restrict__ offsets, const int* __restrict__ wl,
    const int* __restrict__ tokl, const float* __restrict__ ewt,
    float* __restrict__ out) {
  const int wle = wl[blockIdx.y];
  if (wle < 0) return;
  const int e = wle >> 16;
  const int m0 = (wle & 0xffff) << 7;
  const int offs = offsets[e];
  const int Me = offsets[e + 1] - offs;
  const int n0 = blockIdx.x * 256;
  const int t = threadIdx.x, lane = t & 63, wv = t >> 6;
  const int wm = wv & 1, wn = wv >> 1;   // wm,wn in {0,1}

  __shared__ __align__(16) u16 As[128 * 64];
  __shared__ __align__(16) u16 Bs[256 * 64];

  const u16* asrc[4];
#pragma unroll
  for (int p = 0; p < 4; ++p) {
    int c = p * 256 + t;
    int r = c >> 3, c8 = c & 7;
    int row = m0 + r; if (row > Me - 1) row = Me - 1;
    asrc[p] = interm + (size_t)(offs + row) * ID + c8 * 8;
  }
  const u16* bsrc[8];
#pragma unroll
  for (int p = 0; p < 8; ++p) {
    int c = p * 256 + t;
    int r = c >> 3, c8 = c & 7;
    bsrc[p] = wd + ((size_t)e * HD + n0 + r) * ID + c8 * 8;
  }

  f32x4 acc[4][8];
#pragma unroll
  for (int mi = 0; mi < 4; ++mi)
#pragma unroll
    for (int ni = 0; ni < 8; ++ni) acc[mi][ni] = (f32x4){0.f, 0.f, 0.f, 0.f};

  const int lrow = lane & 15, lk = (lane >> 4) * 8;
#pragma unroll 1
  for (int ks = 0; ks < ID / 64; ++ks) {
    __syncthreads();
#pragma unroll
    for (int p = 0; p < 4; ++p)
      async16((char*)As + (p * 256 + wv * 64) * 16, asrc[p]);
#pragma unroll
    for (int p = 0; p < 8; ++p)
      async16((char*)Bs + (p * 256 + wv * 64) * 16, bsrc[p]);
    __syncthreads();
#pragma unroll
    for (int kk = 0; kk < 2; ++kk) {
      bf16x8 af[4], bfr[8];
#pragma unroll
      for (int mi = 0; mi < 4; ++mi)
        af[mi] = *(const bf16x8*)&As[(wm * 64 + mi * 16 + lrow) * 64 + kk * 32 + lk];
#pragma unroll
      for (int ni = 0; ni < 8; ++ni)
        bfr[ni] = *(const bf16x8*)&Bs[(wn * 128 + ni * 16 + lrow) * 64 + kk * 32 + lk];
#pragma unroll
      for (int mi = 0; mi < 4; ++mi)
#pragma unroll
        for (int ni = 0; ni < 8; ++ni)
          acc[mi][ni] = __builtin_amdgcn_mfma_f32_16x16x32_bf16(af[mi], bfr[ni], acc[mi][ni], 0, 0, 0);
    }
#pragma unroll
    for (int p = 0; p < 4; ++p) asrc[p] += 64;
#pragma unroll
    for (int p = 0; p < 8; ++p) bsrc[p] += 64;
  }

#pragma unroll
  for (int mi = 0; mi < 4; ++mi) {
    int rb = wm * 64 + mi * 16 + (lane >> 4) * 4;
#pragma unroll
    for (int j = 0; j < 4; ++j) {
      int row = m0 + rb + j;
      if (row < Me) {
        int aid = tokl[offs + row];
        float w = ewt[aid];
        float* orow = out + (size_t)(aid >> 1) * HD;
#pragma unroll
        for (int ni = 0; ni < 8; ++ni) {
          int col = n0 + wn * 128 + ni * 16 + (lane & 15);
          atomicAdd(orow + col, w * acc[mi][ni][j]);
        }
      }
    }
  }
}

extern "C" void kernel_launch(void* const* d_in, const int* in_sizes, int n_in,
                              void* d_out, int out_size, void* d_ws, size_t ws_size,
                              hipStream_t stream) {
  const float* x    = (const float*)d_in[0];
  const int*   eidx = (const int*)d_in[1];
  const float* ewt  = (const float*)d_in[2];
  const float* gate = (const float*)d_in[3];
  const float* up   = (const float*)d_in[4];
  const float* down = (const float*)d_in[5];
  float* out = (float*)d_out;
  char* ws = (char*)d_ws;

  // layout (total 276,857,856 B == proven budget from rounds 4-7):
  constexpr size_t OFF_INTERM = 0;           // 64 MiB bf16 interm
  constexpr size_t OFF_XB     = 67108864;    // 8 MiB bf16 x
  constexpr size_t OFF_META   = 75497472;    // offsets @ +0, wl @ +64
  constexpr size_t OFF_TOK    = 75498496;    // 32 KiB assignment ids
  constexpr size_t OFF_WD     = 75531264;    // 64 MiB bf16 down
  constexpr size_t OFF_WG     = 142640128;   // 64 MiB bf16 gate
  constexpr size_t OFF_WU     = 209748992;   // 64 MiB bf16 up

  u16* interm  = (u16*)(ws + OFF_INTERM);
  u16* xb      = (u16*)(ws + OFF_XB);
  int* offsets = (int*)(ws + OFF_META);
  int* wl      = (int*)(ws + OFF_META + 64);
  int* tokl    = (int*)(ws + OFF_TOK);
  u16* wd      = (u16*)(ws + OFF_WD);
  u16* wg      = (u16*)(ws + OFF_WG);
  u16* wu      = (u16*)(ws + OFF_WU);

  k_pre<<<dim3(2048), dim3(256), 0, stream>>>(x, gate, up, xb, wg, wu, out);
  k_meta<<<dim3(1), dim3(1024), 0, stream>>>(eidx, offsets, wl, tokl);
  k_g1<<<dim3(64, NWL), dim3(256), 0, stream>>>(xb, wg, wu, down, wd, offsets, wl, tokl, interm);
  k_g2<<<dim3(HD / 256, NWL), dim3(256), 0, stream>>>(interm, wd, offsets, wl, tokl, ewt, out);
}